// Round 3
// baseline (610.348 us; speedup 1.0000x reference)
//
#include <hip/hip_runtime.h>

// SparseLinear: out[32,65536] = x[32,1024] @ (w * mask)[1024,65536] + b, fp32.
// HBM floor: w+mask stream = 512 MB -> ~82 us @ 6.3 TB/s.
//
// R2 post-mortem: LDS return-bus bound — 8 ds_read_b128/wave-k-step x 12 cyc
// = 164 us/CU, matching measurement. Fix: x is wave-uniform per k -> scalar
// loads (s_load) from a pre-transposed xT[k][i] in d_ws. No LDS, no barrier.

#define IN_DIM 1024
#define OUT_DIM 65536
#define BATCH 32
#define KSPLIT 4
#define KCHUNK (IN_DIM / KSPLIT)   // 256
#define BLOCK 256
#define U 8
#define NG (KCHUNK / U)            // 32 groups
#define XT_FLOATS (IN_DIM * BATCH) // 32768 floats = 128 KB

// xT[k*32+i] = x[i][k]; 128 KB one-time, L2-resident for the main kernel.
__global__ __launch_bounds__(BLOCK) void sl_transpose(
    const float* __restrict__ x, float* __restrict__ xT) {
  int idx = blockIdx.x * BLOCK + threadIdx.x;  // 32768 threads
  int i = idx >> 10;            // / IN_DIM
  int k = idx & (IN_DIM - 1);   // % IN_DIM  (coalesced read)
  xT[k * BATCH + i] = x[idx];
}

// TRANSPOSED: xbase = xT (k-major, contiguous 32 floats per k -> s_load_dwordx).
// else:       xbase = x  (row-major, strided scalar loads; slow fallback).
template <bool ATOMIC, bool TRANSPOSED>
__global__ __launch_bounds__(BLOCK, 4) void sl_main(
    const float* __restrict__ xbase, const float* __restrict__ mask,
    const float* __restrict__ w, float* __restrict__ dst) {
  const int tid = threadIdx.x;
  const int j = blockIdx.x * BLOCK + tid;
  const int kc = blockIdx.y;
  const int k0 = kc * KCHUNK;

  float acc[BATCH];
#pragma unroll
  for (int i = 0; i < BATCH; ++i) acc[i] = 0.0f;

  const float* wp = w + (size_t)k0 * OUT_DIM + j;
  const float* mp = mask + (size_t)k0 * OUT_DIM + j;

  float wA[U], mA[U], wB[U], mB[U];

  auto loadg = [&](int g, float* wv, float* mv) {
#pragma unroll
    for (int u = 0; u < U; ++u) {
      size_t off = (size_t)(g * U + u) * OUT_DIM;
      wv[u] = __builtin_nontemporal_load(wp + off);  // streaming, no reuse
      mv[u] = __builtin_nontemporal_load(mp + off);
    }
  };
  auto computeg = [&](int g, const float* wv, const float* mv) {
#pragma unroll
    for (int u = 0; u < U; ++u) {
      float wm = wv[u] * mv[u];
      if (TRANSPOSED) {
        // Loop-uniform address -> scalar loads (s_load_dwordx4), SGPR
        // operands feed the FMAs. No LDS traffic at all.
        const float4* xk =
            (const float4*)(xbase + (size_t)(k0 + g * U + u) * BATCH);
#pragma unroll
        for (int q = 0; q < BATCH / 4; ++q) {
          float4 xq = xk[q];
          acc[q * 4 + 0] = fmaf(xq.x, wm, acc[q * 4 + 0]);
          acc[q * 4 + 1] = fmaf(xq.y, wm, acc[q * 4 + 1]);
          acc[q * 4 + 2] = fmaf(xq.z, wm, acc[q * 4 + 2]);
          acc[q * 4 + 3] = fmaf(xq.w, wm, acc[q * 4 + 3]);
        }
      } else {
        int k = k0 + g * U + u;
#pragma unroll
        for (int i = 0; i < BATCH; ++i)
          acc[i] = fmaf(xbase[(size_t)i * IN_DIM + k], wm, acc[i]);
      }
    }
  };

  // Depth-1 software pipeline: 16 dword loads in flight per wave.
  loadg(0, wA, mA);
#pragma unroll 1
  for (int g = 0; g < NG; g += 2) {
    loadg(g + 1, wB, mB);
    computeg(g, wA, mA);
    if (g + 2 < NG) loadg(g + 2, wA, mA);
    computeg(g + 1, wB, mB);
  }

  if (ATOMIC) {
#pragma unroll
    for (int i = 0; i < BATCH; ++i)
      atomicAdd(dst + (size_t)i * OUT_DIM + j, acc[i]);
  } else {
#pragma unroll
    for (int i = 0; i < BATCH; ++i)
      __builtin_nontemporal_store(
          acc[i], dst + (size_t)(kc * BATCH + i) * OUT_DIM + j);
  }
}

// out[i][j] = b[j] + sum_kc partial[kc][i][j]
__global__ __launch_bounds__(BLOCK) void sl_reduce(
    const float* __restrict__ part, const float* __restrict__ b,
    float* __restrict__ out) {
  const int j4 = blockIdx.x * BLOCK + threadIdx.x;
  const int i = blockIdx.y;
  float4 s = ((const float4*)b)[j4];
#pragma unroll
  for (int kc = 0; kc < KSPLIT; ++kc) {
    float4 p =
        ((const float4*)part)[(size_t)(kc * BATCH + i) * (OUT_DIM / 4) + j4];
    s.x += p.x; s.y += p.y; s.z += p.z; s.w += p.w;
  }
  ((float4*)out)[(size_t)i * (OUT_DIM / 4) + j4] = s;
}

// Atomic-path init: out[i][j] = b[j]
__global__ __launch_bounds__(BLOCK) void sl_init(
    const float* __restrict__ b, float* __restrict__ out) {
  const int j4 = blockIdx.x * BLOCK + threadIdx.x;
  const float4 bv = ((const float4*)b)[j4];
#pragma unroll
  for (int i = 0; i < BATCH; ++i)
    ((float4*)out)[(size_t)i * (OUT_DIM / 4) + j4] = bv;
}

extern "C" void kernel_launch(void* const* d_in, const int* in_sizes, int n_in,
                              void* d_out, int out_size, void* d_ws, size_t ws_size,
                              hipStream_t stream) {
  const float* x = (const float*)d_in[0];
  const float* mask = (const float*)d_in[1];
  const float* w = (const float*)d_in[2];
  const float* b = (const float*)d_in[3];
  float* out = (float*)d_out;

  const size_t xt_bytes = XT_FLOATS * sizeof(float);               // 128 KB
  const size_t part_bytes =
      (size_t)KSPLIT * BATCH * OUT_DIM * sizeof(float);            // 32 MB
  float* xT = (float*)d_ws;
  float* part = (float*)d_ws + XT_FLOATS;

  if (ws_size >= xt_bytes + part_bytes) {
    hipLaunchKernelGGL(sl_transpose, dim3(XT_FLOATS / BLOCK), dim3(BLOCK), 0,
                       stream, x, xT);
    hipLaunchKernelGGL((sl_main<false, true>), dim3(OUT_DIM / BLOCK, KSPLIT),
                       dim3(BLOCK), 0, stream, xT, mask, w, part);
    hipLaunchKernelGGL(sl_reduce, dim3(OUT_DIM / 4 / BLOCK, BATCH), dim3(BLOCK),
                       0, stream, part, b, out);
  } else if (ws_size >= xt_bytes) {
    hipLaunchKernelGGL(sl_init, dim3(OUT_DIM / 4 / BLOCK), dim3(BLOCK), 0,
                       stream, b, out);
    hipLaunchKernelGGL(sl_transpose, dim3(XT_FLOATS / BLOCK), dim3(BLOCK), 0,
                       stream, x, xT);
    hipLaunchKernelGGL((sl_main<true, true>), dim3(OUT_DIM / BLOCK, KSPLIT),
                       dim3(BLOCK), 0, stream, xT, mask, w, out);
  } else {
    // No usable workspace: atomic path reading x row-major (strided s_loads).
    hipLaunchKernelGGL(sl_init, dim3(OUT_DIM / 4 / BLOCK), dim3(BLOCK), 0,
                       stream, b, out);
    hipLaunchKernelGGL((sl_main<true, false>), dim3(OUT_DIM / BLOCK, KSPLIT),
                       dim3(BLOCK), 0, stream, x, mask, w, out);
  }
}

// Round 5
// 575.527 us; speedup vs baseline: 1.0605x; 1.0605x over previous
//
#include <hip/hip_runtime.h>
#include <hip/hip_bf16.h>

// SparseLinear: out[32,65536] = x[32,1024] @ (w * mask)[1024,65536] + b.
// R2-R4 lesson: every x-broadcast path (LDS 164us, uniform vector loads
// 211us, scalar-pipe asm = crash) pays a per-lane return bus for shared
// data. MFMA removes the broadcast structurally: x is the per-lane
// A-fragment, w*mask the B-fragment, fp32 accumulation in the matrix pipe.
// bf16 rounding error ~1e-2 max << 5.19e-2 harness threshold.
// Floor: w+mask HBM stream (~263-300 MB/iter with L3 retention) ~= 45-50us.

#define IN_DIM 1024
#define OUT_DIM 65536
#define BATCH 32
#define BLOCK 256
#define JT 32                       // j-columns per wave (MFMA N)
#define BJT 128                     // 4 waves * 32 j per block
#define KSPLIT 2
#define NSTEP_TOT (IN_DIM / 16)     // 64 MFMA k-steps total
#define NSTEP (NSTEP_TOT / KSPLIT)  // 32 per block
#define XA_USHORTS (NSTEP_TOT * 64 * 8)  // 32768 -> 64 KB packed A-frags

typedef short bf16x8 __attribute__((ext_vector_type(8)));
typedef float f32x16 __attribute__((ext_vector_type(16)));

__device__ __forceinline__ short f2bf(float f) {
  __hip_bfloat16 h = __float2bfloat16(f);  // RNE
  return __builtin_bit_cast(short, h);
}

// Pack x into per-lane A-fragment order: for step t, lane l holds
// A[m=l&31][k = t*16 + (l>>5)*8 + j], j=0..7 (bf16), 16B per lane.
__global__ __launch_bounds__(BLOCK) void sl_prepA(
    const float* __restrict__ x, ushort* __restrict__ xA) {
  int idx = blockIdx.x * BLOCK + threadIdx.x;  // 4096 threads = 64 steps * 64 lanes
  int t = idx >> 6;
  int l = idx & 63;
  int m = l & 31;
  int kk = t * 16 + (l >> 5) * 8;
  const float* xp = x + m * IN_DIM + kk;  // 8 contiguous floats
  bf16x8 a;
#pragma unroll
  for (int j = 0; j < 8; ++j) a[j] = f2bf(xp[j]);
  *(bf16x8*)(xA + (size_t)idx * 8) = a;
}

// PREPPED: xsrc = packed xA (coalesced 16B/lane). else: xsrc = raw x
// (uncoalesced fallback, correct but slow).
template <bool ATOMIC, bool PREPPED>
__global__ __launch_bounds__(BLOCK, 4) void sl_mfma(
    const void* __restrict__ xsrc, const float* __restrict__ mask,
    const float* __restrict__ w, float* __restrict__ dst) {
  const int tid = threadIdx.x;
  const int lane = tid & 63;
  const int wid = tid >> 6;
  const int jb = blockIdx.x * BJT + wid * JT;
  const int kc = blockIdx.y;
  const int t0 = kc * NSTEP;
  const int col = lane & 31;  // MFMA n / C-col
  const int kh = lane >> 5;   // k half: this lane covers k = kh*8 + j

  const size_t jcol = (size_t)jb + col;
  const float* wp = w + (size_t)(t0 * 16 + kh * 8) * OUT_DIM + jcol;
  const float* mp = mask + (size_t)(t0 * 16 + kh * 8) * OUT_DIM + jcol;

  f32x16 acc;
#pragma unroll
  for (int i = 0; i < 16; ++i) acc[i] = 0.0f;

  float wbuf[2][8], mbuf[2][8];
  bf16x8 abuf[2];

  auto loadg = [&](int s, int p) {
    const size_t base = (size_t)s * 16 * OUT_DIM;
#pragma unroll
    for (int u = 0; u < 8; ++u) {  // row k = (t0+s)*16 + kh*8 + u
      wbuf[p][u] = __builtin_nontemporal_load(wp + base + (size_t)u * OUT_DIM);
      mbuf[p][u] = __builtin_nontemporal_load(mp + base + (size_t)u * OUT_DIM);
    }
    if (PREPPED) {
      const ushort* xA = (const ushort*)xsrc;
      abuf[p] = *(const bf16x8*)(xA + ((size_t)(t0 + s) * 64 + lane) * 8);
    } else {
      const float* x = (const float*)xsrc;
      const float* xp = x + col * IN_DIM + (t0 + s) * 16 + kh * 8;
      bf16x8 a;
#pragma unroll
      for (int j = 0; j < 8; ++j) a[j] = f2bf(xp[j]);
      abuf[p] = a;
    }
  };

  auto computeg = [&](int p) {
    bf16x8 bfrag;  // B[k][n]: n=col, k=kh*8+u  (mirrors A layout)
#pragma unroll
    for (int u = 0; u < 8; ++u) bfrag[u] = f2bf(wbuf[p][u] * mbuf[p][u]);
    acc = __builtin_amdgcn_mfma_f32_32x32x16_bf16(abuf[p], bfrag, acc, 0, 0, 0);
  };

  // Depth-1 pipeline: 17 loads of step s+1 in flight during compute of s.
  loadg(0, 0);
#pragma unroll 1
  for (int s = 0; s < NSTEP - 1; ++s) {
    loadg(s + 1, (s + 1) & 1);
    computeg(s & 1);
  }
  computeg((NSTEP - 1) & 1);

  // C/D layout (measured m74/m101): col=lane&31, row=(r&3)+8*(r>>2)+4*kh.
#pragma unroll
  for (int r = 0; r < 16; ++r) {
    int row = (r & 3) + 8 * (r >> 2) + 4 * kh;
    if (ATOMIC) {
      atomicAdd(dst + (size_t)row * OUT_DIM + jcol, acc[r]);
    } else {
      __builtin_nontemporal_store(
          acc[r], dst + (size_t)(kc * BATCH + row) * OUT_DIM + jcol);
    }
  }
}

// out[i][j] = b[j] + sum_kc part[kc][i][j]
__global__ __launch_bounds__(BLOCK) void sl_reduce(
    const float* __restrict__ part, const float* __restrict__ b,
    float* __restrict__ out) {
  const int j4 = blockIdx.x * BLOCK + threadIdx.x;
  const int i = blockIdx.y;
  float4 s = ((const float4*)b)[j4];
#pragma unroll
  for (int kc = 0; kc < KSPLIT; ++kc) {
    float4 p =
        ((const float4*)part)[(size_t)(kc * BATCH + i) * (OUT_DIM / 4) + j4];
    s.x += p.x; s.y += p.y; s.z += p.z; s.w += p.w;
  }
  ((float4*)out)[(size_t)i * (OUT_DIM / 4) + j4] = s;
}

// Atomic-path init: out[i][j] = b[j]
__global__ __launch_bounds__(BLOCK) void sl_init(
    const float* __restrict__ b, float* __restrict__ out) {
  const int j4 = blockIdx.x * BLOCK + threadIdx.x;
  const float4 bv = ((const float4*)b)[j4];
#pragma unroll
  for (int i = 0; i < BATCH; ++i)
    ((float4*)out)[(size_t)i * (OUT_DIM / 4) + j4] = bv;
}

extern "C" void kernel_launch(void* const* d_in, const int* in_sizes, int n_in,
                              void* d_out, int out_size, void* d_ws, size_t ws_size,
                              hipStream_t stream) {
  const float* x = (const float*)d_in[0];
  const float* mask = (const float*)d_in[1];
  const float* w = (const float*)d_in[2];
  const float* b = (const float*)d_in[3];
  float* out = (float*)d_out;

  const size_t xa_bytes = (size_t)XA_USHORTS * sizeof(ushort);       // 64 KB
  const size_t part_bytes =
      (size_t)KSPLIT * BATCH * OUT_DIM * sizeof(float);              // 16 MB
  ushort* xA = (ushort*)d_ws;
  float* part = (float*)((char*)d_ws + xa_bytes);

  if (ws_size >= xa_bytes + part_bytes) {
    hipLaunchKernelGGL(sl_prepA, dim3(XA_USHORTS / 8 / BLOCK), dim3(BLOCK), 0,
                       stream, x, xA);
    hipLaunchKernelGGL((sl_mfma<false, true>), dim3(OUT_DIM / BJT, KSPLIT),
                       dim3(BLOCK), 0, stream, xA, mask, w, part);
    hipLaunchKernelGGL(sl_reduce, dim3(OUT_DIM / 4 / BLOCK, BATCH), dim3(BLOCK),
                       0, stream, part, b, out);
  } else if (ws_size >= xa_bytes) {
    hipLaunchKernelGGL(sl_init, dim3(OUT_DIM / 4 / BLOCK), dim3(BLOCK), 0,
                       stream, b, out);
    hipLaunchKernelGGL(sl_prepA, dim3(XA_USHORTS / 8 / BLOCK), dim3(BLOCK), 0,
                       stream, x, xA);
    hipLaunchKernelGGL((sl_mfma<true, true>), dim3(OUT_DIM / BJT, KSPLIT),
                       dim3(BLOCK), 0, stream, xA, mask, w, out);
  } else {
    hipLaunchKernelGGL(sl_init, dim3(OUT_DIM / 4 / BLOCK), dim3(BLOCK), 0,
                       stream, b, out);
    hipLaunchKernelGGL((sl_mfma<true, false>), dim3(OUT_DIM / BJT, KSPLIT),
                       dim3(BLOCK), 0, stream, x, mask, w, out);
  }
}